// Round 9
// baseline (416.643 us; speedup 1.0000x reference)
//
#include <hip/hip_runtime.h>

// ---------------------------------------------------------------------------
// MHA forward, fp32 I/O.  S=4096, D=1024, NH=16, HD=64.
// R9: attention occupancy fix.  R8 was latency-bound (1 wave/block, 2
// waves/SIMD, both pipes <16% busy).  Now: 256-thr blocks = 4 waves, each
// wave runs the SAME barrier-free R8 loop over a private kv QUARTER (zero-
// shift softmax => partials are purely additive), then a 2-barrier LDS
// combine (waves 1-3 write oacc+l, wave 0 sums/normalizes/stores).
// 2048 blocks x 4 waves, ~76 VGPR -> 6 blocks/CU = 24 waves/CU (3x R8).
// GEMM/prep unchanged from R8.
// ---------------------------------------------------------------------------

typedef unsigned short ushort_t;
typedef unsigned short ushort4v __attribute__((ext_vector_type(4)));
typedef unsigned short ushort8 __attribute__((ext_vector_type(8)));
typedef __bf16 bf16x8 __attribute__((ext_vector_type(8)));
typedef float f32x4 __attribute__((ext_vector_type(4)));
typedef float f32x16 __attribute__((ext_vector_type(16)));

#define SEQ 4096
#define DIM 1024
#define NH 16
#define HD 64
// 0.125 * log2(e): folded into Q projection so softmax uses exp2 directly
#define QSCALE 0.18033688011112042f

__device__ inline ushort_t fcvt(float f) {           // native f32->bf16 RTNE
    return __builtin_bit_cast(ushort_t, (__bf16)f);
}
__device__ inline bf16x8 frag_of(ushort8 t) {
    return __builtin_bit_cast(bf16x8, t);
}
__device__ inline bf16x8 lds_frag(const ushort_t* p) {
    return frag_of(*(const ushort8*)p);
}
__device__ inline void gload_lds16(const void* g, void* l) {
    __builtin_amdgcn_global_load_lds(
        (const __attribute__((address_space(1))) void*)g,
        (__attribute__((address_space(3))) void*)l, 16, 0, 0);
}

// ---------------------------------------------------------------------------
// Prep: f32 -> bf16, 2 tensors selected by blockIdx.y (8 elems/thread)
// ---------------------------------------------------------------------------
__global__ __launch_bounds__(256) void cvt2(
    const float* __restrict__ s0, ushort_t* __restrict__ d0,
    const float* __restrict__ s1, ushort_t* __restrict__ d1, int n8)
{
    const float* s = blockIdx.y ? s1 : s0;
    ushort_t*    d = blockIdx.y ? d1 : d0;
    int i = blockIdx.x * 256 + threadIdx.x;
    if (i >= n8) return;
    const f32x4* sp = (const f32x4*)s + (size_t)i * 2;
    f32x4 a = sp[0], b = sp[1];
    ushort8 o;
    for (int k = 0; k < 4; ++k) { o[k] = fcvt(a[k]); o[k + 4] = fcvt(b[k]); }
    *((ushort8*)d + i) = o;
}

// Prep: f32 -> bf16, 4 tensors selected by blockIdx.y
__global__ __launch_bounds__(256) void cvt4(
    const float* __restrict__ s0, ushort_t* __restrict__ d0,
    const float* __restrict__ s1, ushort_t* __restrict__ d1,
    const float* __restrict__ s2, ushort_t* __restrict__ d2,
    const float* __restrict__ s3, ushort_t* __restrict__ d3, int n8)
{
    const float* ss[4] = {s0, s1, s2, s3};
    ushort_t*    dd[4] = {d0, d1, d2, d3};
    const float* s = ss[blockIdx.y];
    ushort_t*    d = dd[blockIdx.y];
    int i = blockIdx.x * 256 + threadIdx.x;
    if (i >= n8) return;
    const f32x4* sp = (const f32x4*)s + (size_t)i * 2;
    f32x4 a = sp[0], b = sp[1];
    ushort8 o;
    for (int k = 0; k < 4; ++k) { o[k] = fcvt(a[k]); o[k + 4] = fcvt(b[k]); }
    *((ushort8*)d + i) = o;
}

// ---------------------------------------------------------------------------
// GEMM: C[4096,1024] = A @ W^T + bias (then * scale), all bf16 in.  BK=64.
// Tile 128x64, 256 thr = 4 waves 2x2, each wave 64x32 of 16x16x32 MFMA.
// TRANS_OUT: store C^T[col][row] (for V^T), b64 vector stores.
// grid = (16, 32) = 512 blocks.
// ---------------------------------------------------------------------------
template <bool OUT_F32, bool TRANS_OUT>
__global__ __launch_bounds__(256) void gemm_bf16(
    const ushort_t* __restrict__ A, const ushort_t* __restrict__ W,
    const float* __restrict__ bias, void* __restrict__ Cv, float scale)
{
    __shared__ __align__(16) ushort_t sA[128 * 64];
    __shared__ __align__(16) ushort_t sB[64 * 64];

    const int tid  = threadIdx.x;
    const int w    = tid >> 6;
    const int lane = tid & 63;
    const int quad = lane >> 4;
    const int l15  = lane & 15;
    const int wm   = w >> 1;
    const int wn   = w & 1;
    const int m0   = blockIdx.y * 128;
    const int n0   = blockIdx.x * 64;

    f32x4 acc[4][2] = {};

    for (int kt = 0; kt < DIM; kt += 64) {
        __syncthreads();
        for (int r = 0; r < 4; ++r) {           // A tile 128x64: 1024 chunks
            int c = r * 256 + tid;
            gload_lds16(A + (size_t)(m0 + (c >> 3)) * DIM + kt + ((c & 7) << 3),
                        (char*)sA + (r * 256 + (tid & ~63)) * 16);
        }
        for (int r = 0; r < 2; ++r) {           // B tile 64x64: 512 chunks
            int c = r * 256 + tid;
            gload_lds16(W + (size_t)(n0 + (c >> 3)) * DIM + kt + ((c & 7) << 3),
                        (char*)sB + (r * 256 + (tid & ~63)) * 16);
        }
        __syncthreads();

        for (int ks = 0; ks < 2; ++ks) {
            bf16x8 af[4], bf[2];
            for (int i = 0; i < 4; ++i)
                af[i] = lds_frag(sA + (wm * 64 + i * 16 + l15) * 64 + ks * 32 + quad * 8);
            for (int j = 0; j < 2; ++j)
                bf[j] = lds_frag(sB + (wn * 32 + j * 16 + l15) * 64 + ks * 32 + quad * 8);
            for (int i = 0; i < 4; ++i)
                for (int j = 0; j < 2; ++j)
                    acc[i][j] = __builtin_amdgcn_mfma_f32_16x16x32_bf16(
                        af[i], bf[j], acc[i][j], 0, 0, 0);
        }
    }

    // epilogue: C/D layout col=lane&15, row=quad*4+reg
    for (int j = 0; j < 2; ++j) {
        int col = n0 + wn * 32 + j * 16 + l15;
        float bj = bias[col];
        for (int i = 0; i < 4; ++i) {
            int row = m0 + wm * 64 + i * 16 + quad * 4;
            if constexpr (TRANS_OUT) {
                ushort4v o4;
                for (int r = 0; r < 4; ++r) o4[r] = fcvt((acc[i][j][r] + bj) * scale);
                *(ushort4v*)((ushort_t*)Cv + (size_t)col * SEQ + row) = o4;
            } else if constexpr (OUT_F32) {
                for (int r = 0; r < 4; ++r)
                    ((float*)Cv)[(size_t)(row + r) * DIM + col] = acc[i][j][r] + bj;
            } else {
                for (int r = 0; r < 4; ++r)
                    ((ushort_t*)Cv)[(size_t)(row + r) * DIM + col] =
                        fcvt((acc[i][j][r] + bj) * scale);
            }
        }
    }
}

// ---------------------------------------------------------------------------
// Flash attention, 32x32x16 MFMA, zero-shift softmax, barrier-free kv loop.
// Block = 256 thr = 4 waves; ALL waves share the same 32 q rows, each wave
// owns a private kv QUARTER (SEQ/4, step 64).  Partials are additive (no
// running max), combined through LDS at the end (2 barriers total).
// grid = (SEQ/32, NH) = (128, 16) = 2048 blocks -> ~6 blocks/CU resident.
// ---------------------------------------------------------------------------
__global__ __launch_bounds__(256) void attn_kernel(
    const ushort_t* __restrict__ Q, const ushort_t* __restrict__ K,
    const ushort_t* __restrict__ VT, ushort_t* __restrict__ O)
{
    // union: per-wave P^T tiles (in-loop) / f32 combine buffer (post-loop)
    __shared__ __align__(16) char smem[3 * 64 * 33 * 4];  // 25344 B
    ushort_t* sPbase = (ushort_t*)smem;
    float*    cb     = (float*)smem;

    const int tid  = threadIdx.x;
    const int w    = tid >> 6;          // wave 0..3 = kv quarter
    const int lane = tid & 63;
    const int l31  = lane & 31;
    const int hi   = lane >> 5;         // 0..1
    const int h    = blockIdx.y;
    const int q0   = blockIdx.x * 32;
    const int hHD  = h * HD;

    ushort_t* sP = sPbase + w * (32 * 72);   // wave-private P^T [32 q][64+pad]

    // Q B-frags direct from global: n=q=l31, k=d=ks*16+hi*8+j
    const ushort_t* qb = Q + (size_t)(q0 + l31) * DIM + hHD + hi * 8;
    bf16x8 qf[4];
    for (int ks = 0; ks < 4; ++ks)
        qf[ks] = frag_of(*(const ushort8*)(qb + ks * 16));

    // base pointers for K (A-frag rows kv) and V^T (A-frag rows d)
    const ushort_t* kb = K  + (size_t)l31 * DIM + hHD + hi * 8;
    const ushort_t* vb = VT + (size_t)(hHD + l31) * SEQ + hi * 8;

    f32x16 oacc[2] = {};    // O^T: col q=l31, row d=(r&3)+8(r>>2)+4hi+32dt
    float l_i = 0.f;

    const int kvbeg = w * (SEQ / 4), kvend = kvbeg + SEQ / 4;
    for (int kv0 = kvbeg; kv0 < kvend; kv0 += 64) {
        // K A-frags: m=kv=t*32+l31, k=d=ks*16+hi*8+j  -> 8 b128 loads
        ushort8 kf[8];
        for (int t = 0; t < 2; ++t)
            for (int ks = 0; ks < 4; ++ks)
                kf[t * 4 + ks] = *(const ushort8*)(
                    kb + (size_t)(kv0 + t * 32) * DIM + ks * 16);

        // S^T = K @ Q^T
        f32x16 sacc[2] = {};
        for (int t = 0; t < 2; ++t)
            for (int ks = 0; ks < 4; ++ks)
                sacc[t] = __builtin_amdgcn_mfma_f32_32x32x16_bf16(
                    frag_of(kf[t * 4 + ks]), qf[ks], sacc[t], 0, 0, 0);

        // V^T A-frags issued before the exp chain (fetch overlaps exp)
        ushort8 vf[8];
        for (int ks = 0; ks < 4; ++ks)
            for (int dt = 0; dt < 2; ++dt)
                vf[ks * 2 + dt] = *(const ushort8*)(
                    vb + (size_t)(dt * 32) * SEQ + kv0 + ks * 16);

        // zero-shift softmax: p = exp2(s), raw v_exp_f32
        float lp = 0.f;
        for (int t = 0; t < 2; ++t)
            for (int r = 0; r < 16; ++r) {
                float p = __builtin_amdgcn_exp2f(sacc[t][r]);
                sacc[t][r] = p;
                lp += p;
            }
        l_i += lp + __shfl_xor(lp, 32);   // lanes l, l+32 share column q

        // P^T -> LDS [q=l31][kv]: kv = t*32 + g*8 + hi*4 + r  (b64 writes)
        for (int t = 0; t < 2; ++t)
            for (int g = 0; g < 4; ++g) {
                ushort4v pk;
                for (int r = 0; r < 4; ++r) pk[r] = fcvt(sacc[t][g * 4 + r]);
                *(ushort4v*)(sP + l31 * 72 + t * 32 + g * 8 + hi * 4) = pk;
            }

        // O^T += V^T @ P^T  (in-wave lgkmcnt orders sP write->read)
        for (int ks = 0; ks < 4; ++ks) {
            bf16x8 pf = lds_frag(sP + l31 * 72 + ks * 16 + hi * 8);
            for (int dt = 0; dt < 2; ++dt)
                oacc[dt] = __builtin_amdgcn_mfma_f32_32x32x16_bf16(
                    frag_of(vf[ks * 2 + dt]), pf, oacc[dt], 0, 0, 0);
        }
    }

    // ---- combine 4 wave-partials (additive: zero-shift softmax) ----
    __syncthreads();                       // all waves done; sP regions dead
    if (w > 0) {                           // waves 1-3 publish partials
        float* my = cb + ((w - 1) * 64 + lane) * 33;
        for (int dt = 0; dt < 2; ++dt)
            for (int r = 0; r < 16; ++r) my[dt * 16 + r] = oacc[dt][r];
        my[32] = l_i;
    }
    __syncthreads();
    if (w == 0) {
        for (int j = 0; j < 3; ++j) {
            const float* pj = cb + (j * 64 + lane) * 33;
            for (int dt = 0; dt < 2; ++dt)
                for (int r = 0; r < 16; ++r) oacc[dt][r] += pj[dt * 16 + r];
            l_i += pj[32];
        }
        // epilogue: O[q][hHD+d], d=(r&3)+8g+4hi+32dt -> b64 stores
        float inv = 1.f / l_i;
        int qrow = q0 + l31;
        for (int dt = 0; dt < 2; ++dt)
            for (int g = 0; g < 4; ++g) {
                ushort4v o4;
                for (int r = 0; r < 4; ++r)
                    o4[r] = fcvt(oacc[dt][g * 4 + r] * inv);
                *(ushort4v*)(O + (size_t)qrow * DIM + hHD +
                             dt * 32 + g * 8 + hi * 4) = o4;
            }
    }
}

// ---------------------------------------------------------------------------
extern "C" void kernel_launch(void* const* d_in, const int* in_sizes, int n_in,
                              void* d_out, int out_size, void* d_ws, size_t ws_size,
                              hipStream_t stream)
{
    const float* q   = (const float*)d_in[0];
    const float* kv  = (const float*)d_in[1];
    const float* q_w = (const float*)d_in[2];
    const float* q_b = (const float*)d_in[3];
    const float* k_w = (const float*)d_in[4];
    const float* k_b = (const float*)d_in[5];
    const float* v_w = (const float*)d_in[6];
    const float* v_b = (const float*)d_in[7];
    const float* o_w = (const float*)d_in[8];
    const float* o_b = (const float*)d_in[9];
    float* out = (float*)d_out;

    const size_t SD = (size_t)SEQ * DIM;
    const size_t WW = (size_t)DIM * DIM;
    ushort_t* Qp  = (ushort_t*)d_ws;          // bf16, pre-scaled by QSCALE
    ushort_t* Kp  = Qp + SD;
    ushort_t* VpT = Kp + SD;                  // V^T: [DIM][SEQ]
    ushort_t* AO  = VpT + SD;                 // attention out; aliases Qb
    ushort_t* Qb  = AO;                       // bf16(q) — dead before AO write
    ushort_t* KVb = AO + SD;
    ushort_t* qwb = KVb + SD;
    ushort_t* kwb = qwb + WW;
    ushort_t* vwb = kwb + WW;
    ushort_t* owb = vwb + WW;

    // prep: 2 launches
    cvt2<<<dim3((unsigned)(SD / 8 / 256), 2), 256, 0, stream>>>(
        q, Qb, kv, KVb, (int)(SD / 8));
    cvt4<<<dim3((unsigned)(WW / 8 / 256), 4), 256, 0, stream>>>(
        q_w, qwb, k_w, kwb, v_w, vwb, o_w, owb, (int)(WW / 8));

    dim3 gg(DIM / 64, SEQ / 128);   // (16, 32)
    gemm_bf16<false, false><<<gg, 256, 0, stream>>>(Qb,  qwb, q_b, Qp,  QSCALE);
    gemm_bf16<false, false><<<gg, 256, 0, stream>>>(KVb, kwb, k_b, Kp,  1.0f);
    gemm_bf16<false, true ><<<gg, 256, 0, stream>>>(KVb, vwb, v_b, VpT, 1.0f);
    attn_kernel<<<dim3(SEQ / 32, NH), 256, 0, stream>>>(Qp, Kp, VpT, AO);
    gemm_bf16<true,  false><<<gg, 256, 0, stream>>>(AO, owb, o_b, out, 1.0f);
}

// Round 11
// 281.348 us; speedup vs baseline: 1.4809x; 1.4809x over previous
//
#include <hip/hip_runtime.h>

// ---------------------------------------------------------------------------
// MHA forward, fp32 I/O.  S=4096, D=1024, NH=16, HD=64.
// R11 = R10 with the compile fix (kf/vf are bf16x8 already; drop frag_of).
// Attention = coalesced LDS staging (kills R8/R9's L1-thrashing strided
// global frags) + software-pipelined double buffer (kills R7's serial
// stage->barrier->compute).  256 thr = 4 waves x 32 q (q-tile 128, full kv
// per wave, no combine); kv tile 64; K/V double-buffered in LDS (36.9 KB);
// P^T scratch REUSES the current buffer (K/V already in regs).  2 barriers
// per iter, staging loads issued ~1000 cyc before their vmcnt drain.
// Grid (NH, S/128): head fastest -> XCD = h%8 -> 2 heads/XCD L2-resident.
// GEMM/prep unchanged from R9.
// ---------------------------------------------------------------------------

typedef unsigned short ushort_t;
typedef unsigned short ushort4v __attribute__((ext_vector_type(4)));
typedef unsigned short ushort8 __attribute__((ext_vector_type(8)));
typedef __bf16 bf16x8 __attribute__((ext_vector_type(8)));
typedef float f32x4 __attribute__((ext_vector_type(4)));
typedef float f32x16 __attribute__((ext_vector_type(16)));

#define SEQ 4096
#define DIM 1024
#define NH 16
#define HD 64
// 0.125 * log2(e): folded into Q projection so softmax uses exp2 directly
#define QSCALE 0.18033688011112042f

__device__ inline ushort_t fcvt(float f) {           // native f32->bf16 RTNE
    return __builtin_bit_cast(ushort_t, (__bf16)f);
}
__device__ inline bf16x8 frag_of(ushort8 t) {
    return __builtin_bit_cast(bf16x8, t);
}
__device__ inline bf16x8 lds_frag(const ushort_t* p) {
    return frag_of(*(const ushort8*)p);
}
__device__ inline void gload_lds16(const void* g, void* l) {
    __builtin_amdgcn_global_load_lds(
        (const __attribute__((address_space(1))) void*)g,
        (__attribute__((address_space(3))) void*)l, 16, 0, 0);
}

// ---------------------------------------------------------------------------
// Prep: f32 -> bf16, 2 tensors selected by blockIdx.y (8 elems/thread)
// ---------------------------------------------------------------------------
__global__ __launch_bounds__(256) void cvt2(
    const float* __restrict__ s0, ushort_t* __restrict__ d0,
    const float* __restrict__ s1, ushort_t* __restrict__ d1, int n8)
{
    const float* s = blockIdx.y ? s1 : s0;
    ushort_t*    d = blockIdx.y ? d1 : d0;
    int i = blockIdx.x * 256 + threadIdx.x;
    if (i >= n8) return;
    const f32x4* sp = (const f32x4*)s + (size_t)i * 2;
    f32x4 a = sp[0], b = sp[1];
    ushort8 o;
    for (int k = 0; k < 4; ++k) { o[k] = fcvt(a[k]); o[k + 4] = fcvt(b[k]); }
    *((ushort8*)d + i) = o;
}

// Prep: f32 -> bf16, 4 tensors selected by blockIdx.y
__global__ __launch_bounds__(256) void cvt4(
    const float* __restrict__ s0, ushort_t* __restrict__ d0,
    const float* __restrict__ s1, ushort_t* __restrict__ d1,
    const float* __restrict__ s2, ushort_t* __restrict__ d2,
    const float* __restrict__ s3, ushort_t* __restrict__ d3, int n8)
{
    const float* ss[4] = {s0, s1, s2, s3};
    ushort_t*    dd[4] = {d0, d1, d2, d3};
    const float* s = ss[blockIdx.y];
    ushort_t*    d = dd[blockIdx.y];
    int i = blockIdx.x * 256 + threadIdx.x;
    if (i >= n8) return;
    const f32x4* sp = (const f32x4*)s + (size_t)i * 2;
    f32x4 a = sp[0], b = sp[1];
    ushort8 o;
    for (int k = 0; k < 4; ++k) { o[k] = fcvt(a[k]); o[k + 4] = fcvt(b[k]); }
    *((ushort8*)d + i) = o;
}

// ---------------------------------------------------------------------------
// GEMM: C[4096,1024] = A @ W^T + bias (then * scale), all bf16 in.  BK=64.
// Tile 128x64, 256 thr = 4 waves 2x2, each wave 64x32 of 16x16x32 MFMA.
// TRANS_OUT: store C^T[col][row] (for V^T), b64 vector stores.
// grid = (16, 32) = 512 blocks.
// ---------------------------------------------------------------------------
template <bool OUT_F32, bool TRANS_OUT>
__global__ __launch_bounds__(256) void gemm_bf16(
    const ushort_t* __restrict__ A, const ushort_t* __restrict__ W,
    const float* __restrict__ bias, void* __restrict__ Cv, float scale)
{
    __shared__ __align__(16) ushort_t sA[128 * 64];
    __shared__ __align__(16) ushort_t sB[64 * 64];

    const int tid  = threadIdx.x;
    const int w    = tid >> 6;
    const int lane = tid & 63;
    const int quad = lane >> 4;
    const int l15  = lane & 15;
    const int wm   = w >> 1;
    const int wn   = w & 1;
    const int m0   = blockIdx.y * 128;
    const int n0   = blockIdx.x * 64;

    f32x4 acc[4][2] = {};

    for (int kt = 0; kt < DIM; kt += 64) {
        __syncthreads();
        for (int r = 0; r < 4; ++r) {           // A tile 128x64: 1024 chunks
            int c = r * 256 + tid;
            gload_lds16(A + (size_t)(m0 + (c >> 3)) * DIM + kt + ((c & 7) << 3),
                        (char*)sA + (r * 256 + (tid & ~63)) * 16);
        }
        for (int r = 0; r < 2; ++r) {           // B tile 64x64: 512 chunks
            int c = r * 256 + tid;
            gload_lds16(W + (size_t)(n0 + (c >> 3)) * DIM + kt + ((c & 7) << 3),
                        (char*)sB + (r * 256 + (tid & ~63)) * 16);
        }
        __syncthreads();

        for (int ks = 0; ks < 2; ++ks) {
            bf16x8 af[4], bf[2];
            for (int i = 0; i < 4; ++i)
                af[i] = lds_frag(sA + (wm * 64 + i * 16 + l15) * 64 + ks * 32 + quad * 8);
            for (int j = 0; j < 2; ++j)
                bf[j] = lds_frag(sB + (wn * 32 + j * 16 + l15) * 64 + ks * 32 + quad * 8);
            for (int i = 0; i < 4; ++i)
                for (int j = 0; j < 2; ++j)
                    acc[i][j] = __builtin_amdgcn_mfma_f32_16x16x32_bf16(
                        af[i], bf[j], acc[i][j], 0, 0, 0);
        }
    }

    // epilogue: C/D layout col=lane&15, row=quad*4+reg
    for (int j = 0; j < 2; ++j) {
        int col = n0 + wn * 32 + j * 16 + l15;
        float bj = bias[col];
        for (int i = 0; i < 4; ++i) {
            int row = m0 + wm * 64 + i * 16 + quad * 4;
            if constexpr (TRANS_OUT) {
                ushort4v o4;
                for (int r = 0; r < 4; ++r) o4[r] = fcvt((acc[i][j][r] + bj) * scale);
                *(ushort4v*)((ushort_t*)Cv + (size_t)col * SEQ + row) = o4;
            } else if constexpr (OUT_F32) {
                for (int r = 0; r < 4; ++r)
                    ((float*)Cv)[(size_t)(row + r) * DIM + col] = acc[i][j][r] + bj;
            } else {
                for (int r = 0; r < 4; ++r)
                    ((ushort_t*)Cv)[(size_t)(row + r) * DIM + col] =
                        fcvt((acc[i][j][r] + bj) * scale);
            }
        }
    }
}

// ---------------------------------------------------------------------------
// Flash attention, 32x32x16 MFMA, zero-shift softmax, pipelined LDS staging.
// Block = 256 thr = 4 waves, q-tile 128 (wave w owns q rows q0+w*32+l31,
// FULL kv range -> no combine).  kv tiles of 64, double-buffered K+V in LDS
// (stride 72, coalesced b128 staging).  P^T scratch reuses the CURRENT
// buffer (its K/V already consumed into registers before barrier 1).
// grid = (NH, SEQ/128) = (16, 32): head fastest -> XCD = h%8 (L2 locality).
// ---------------------------------------------------------------------------
#define BUFE (2 * 64 * 72)                 // elems per buffer (K half + V half)
__global__ __launch_bounds__(256) void attn_kernel(
    const ushort_t* __restrict__ Q, const ushort_t* __restrict__ K,
    const ushort_t* __restrict__ VT, ushort_t* __restrict__ O)
{
    __shared__ __align__(16) ushort_t sB[2 * BUFE];   // 36864 B

    const int tid  = threadIdx.x;
    const int w    = tid >> 6;          // wave 0..3
    const int lane = tid & 63;
    const int l31  = lane & 31;
    const int hi   = lane >> 5;         // 0..1
    const int h    = blockIdx.x;
    const int q0   = blockIdx.y * 128 + w * 32;
    const int hHD  = h * HD;

    // staging indices: thread handles chunks c = tid, tid+256 (of 512)
    const int srow0 = tid >> 3;                  // 0..31
    const int srow1 = (tid + 256) >> 3;          // 32..63
    const int sch   = (tid & 7) << 3;            // 0,8,...,56
    const ushort_t* Kg0 = K  + (size_t)srow0 * DIM + hHD + sch;
    const ushort_t* Kg1 = K  + (size_t)srow1 * DIM + hHD + sch;
    const ushort_t* Vg0 = VT + (size_t)(hHD + srow0) * SEQ + sch;
    const ushort_t* Vg1 = VT + (size_t)(hHD + srow1) * SEQ + sch;
    const int l0 = srow0 * 72 + sch, l1 = srow1 * 72 + sch;

    // Q B-frags direct from global (once): n=q=l31, k=d=ks*16+hi*8+j
    const ushort_t* qb = Q + (size_t)(q0 + l31) * DIM + hHD + hi * 8;
    bf16x8 qf[4];
    for (int ks = 0; ks < 4; ++ks)
        qf[ks] = frag_of(*(const ushort8*)(qb + ks * 16));

    // prologue: stage tile 0 into buffer 0
    *(ushort8*)(sB + l0)        = *(const ushort8*)(Kg0);
    *(ushort8*)(sB + l1)        = *(const ushort8*)(Kg1);
    *(ushort8*)(sB + 4608 + l0) = *(const ushort8*)(Vg0);
    *(ushort8*)(sB + 4608 + l1) = *(const ushort8*)(Vg1);
    __syncthreads();

    f32x16 oacc[2] = {};    // O^T: col q=l31, row d=(r&3)+8(r>>2)+4hi+32dt
    float l_i = 0.f;

    for (int it = 0; it < SEQ / 64; ++it) {
        const int cur = it & 1;
        const int kvn = (it + 1) * 64;
        ushort_t* bK = sB + cur * BUFE;
        ushort_t* bV = bK + 4608;

        // A: issue next tile's global loads (drain ~1 iter later -> hidden)
        ushort8 gk0, gk1, gv0, gv1;
        if (kvn < SEQ) {
            gk0 = *(const ushort8*)(Kg0 + (size_t)kvn * DIM);
            gk1 = *(const ushort8*)(Kg1 + (size_t)kvn * DIM);
            gv0 = *(const ushort8*)(Vg0 + kvn);
            gv1 = *(const ushort8*)(Vg1 + kvn);
        }

        // B: fragment reads from current buffer (regs) -- K and V both
        bf16x8 kf[8], vf[8];
        for (int t = 0; t < 2; ++t)
            for (int ks = 0; ks < 4; ++ks)
                kf[t * 4 + ks] = lds_frag(bK + (t * 32 + l31) * 72 + ks * 16 + hi * 8);
        for (int ks = 0; ks < 4; ++ks)
            for (int dt = 0; dt < 2; ++dt)
                vf[ks * 2 + dt] = lds_frag(bV + (dt * 32 + l31) * 72 + ks * 16 + hi * 8);

        // C: S^T = K @ Q^T
        f32x16 sacc[2] = {};
        for (int t = 0; t < 2; ++t)
            for (int ks = 0; ks < 4; ++ks)
                sacc[t] = __builtin_amdgcn_mfma_f32_32x32x16_bf16(
                    kf[t * 4 + ks], qf[ks], sacc[t], 0, 0, 0);

        __syncthreads();   // barrier 1: all waves' frag reads done -> cur buf free

        // E: zero-shift softmax, raw v_exp_f32
        float lp = 0.f;
        for (int t = 0; t < 2; ++t)
            for (int r = 0; r < 16; ++r) {
                float p = __builtin_amdgcn_exp2f(sacc[t][r]);
                sacc[t][r] = p;
                lp += p;
            }
        l_i += lp + __shfl_xor(lp, 32);

        // F: P^T -> scratch in CURRENT buffer (wave-private slice)
        ushort_t* pw = bK + w * 2304;       // 32 rows x 72
        for (int t = 0; t < 2; ++t)
            for (int g = 0; g < 4; ++g) {
                ushort4v pk;
                for (int r = 0; r < 4; ++r) pk[r] = fcvt(sacc[t][g * 4 + r]);
                *(ushort4v*)(pw + l31 * 72 + t * 32 + g * 8 + hi * 4) = pk;
            }

        // G: O^T += V^T @ P^T (in-wave lgkmcnt orders scratch write->read)
        for (int ks = 0; ks < 4; ++ks) {
            bf16x8 pf = lds_frag(pw + l31 * 72 + ks * 16 + hi * 8);
            for (int dt = 0; dt < 2; ++dt)
                oacc[dt] = __builtin_amdgcn_mfma_f32_32x32x16_bf16(
                    vf[ks * 2 + dt], pf, oacc[dt], 0, 0, 0);
        }

        // H: commit staged tile into other buffer
        if (kvn < SEQ) {
            ushort_t* nB = sB + (cur ^ 1) * BUFE;
            *(ushort8*)(nB + l0)        = gk0;
            *(ushort8*)(nB + l1)        = gk1;
            *(ushort8*)(nB + 4608 + l0) = gv0;
            *(ushort8*)(nB + 4608 + l1) = gv1;
        }
        __syncthreads();   // barrier 2: scratch reads done + staged writes visible
    }

    // epilogue: O[q][hHD+d], d=(r&3)+8g+4hi+32dt -> b64 stores per (dt,g)
    float inv = 1.f / l_i;
    int qrow = q0 + l31;
    for (int dt = 0; dt < 2; ++dt)
        for (int g = 0; g < 4; ++g) {
            ushort4v o4;
            for (int r = 0; r < 4; ++r) o4[r] = fcvt(oacc[dt][g * 4 + r] * inv);
            *(ushort4v*)(O + (size_t)qrow * DIM + hHD + dt * 32 + g * 8 + hi * 4) = o4;
        }
}

// ---------------------------------------------------------------------------
extern "C" void kernel_launch(void* const* d_in, const int* in_sizes, int n_in,
                              void* d_out, int out_size, void* d_ws, size_t ws_size,
                              hipStream_t stream)
{
    const float* q   = (const float*)d_in[0];
    const float* kv  = (const float*)d_in[1];
    const float* q_w = (const float*)d_in[2];
    const float* q_b = (const float*)d_in[3];
    const float* k_w = (const float*)d_in[4];
    const float* k_b = (const float*)d_in[5];
    const float* v_w = (const float*)d_in[6];
    const float* v_b = (const float*)d_in[7];
    const float* o_w = (const float*)d_in[8];
    const float* o_b = (const float*)d_in[9];
    float* out = (float*)d_out;

    const size_t SD = (size_t)SEQ * DIM;
    const size_t WW = (size_t)DIM * DIM;
    ushort_t* Qp  = (ushort_t*)d_ws;          // bf16, pre-scaled by QSCALE
    ushort_t* Kp  = Qp + SD;
    ushort_t* VpT = Kp + SD;                  // V^T: [DIM][SEQ]
    ushort_t* AO  = VpT + SD;                 // attention out; aliases Qb
    ushort_t* Qb  = AO;                       // bf16(q) — dead before AO write
    ushort_t* KVb = AO + SD;
    ushort_t* qwb = KVb + SD;
    ushort_t* kwb = qwb + WW;
    ushort_t* vwb = kwb + WW;
    ushort_t* owb = vwb + WW;

    // prep: 2 launches
    cvt2<<<dim3((unsigned)(SD / 8 / 256), 2), 256, 0, stream>>>(
        q, Qb, kv, KVb, (int)(SD / 8));
    cvt4<<<dim3((unsigned)(WW / 8 / 256), 4), 256, 0, stream>>>(
        q_w, qwb, k_w, kwb, v_w, vwb, o_w, owb, (int)(WW / 8));

    dim3 gg(DIM / 64, SEQ / 128);   // (16, 32)
    gemm_bf16<false, false><<<gg, 256, 0, stream>>>(Qb,  qwb, q_b, Qp,  QSCALE);
    gemm_bf16<false, false><<<gg, 256, 0, stream>>>(KVb, kwb, k_b, Kp,  1.0f);
    gemm_bf16<false, true ><<<gg, 256, 0, stream>>>(KVb, vwb, v_b, VpT, 1.0f);
    attn_kernel<<<dim3(NH, SEQ / 128), 256, 0, stream>>>(Qp, Kp, VpT, AO);
    gemm_bf16<true,  false><<<gg, 256, 0, stream>>>(AO, owb, o_b, out, 1.0f);
}

// Round 12
// 271.630 us; speedup vs baseline: 1.5339x; 1.0358x over previous
//
#include <hip/hip_runtime.h>

// ---------------------------------------------------------------------------
// MHA forward, fp32 I/O.  S=4096, D=1024, NH=16, HD=64.
// R12: GEMM rebuilt on the R11-attn pipeline pattern: register-staged
// double-buffered LDS (1 barrier/iter, staging loads issued a full iter
// ahead), LDS row stride 40 elems (bank advance 20 mod 32 -> 2-way = free;
// old stride-64 gave 16-way conflicts on every frag read), BK=32, and the
// three projection GEMMs fused into ONE z-indexed launch (1536 blocks ->
// ~5 blocks/CU vs 2).  Attention unchanged from R11 (109.7 us, 626 TF).
// ---------------------------------------------------------------------------

typedef unsigned short ushort_t;
typedef unsigned short ushort4v __attribute__((ext_vector_type(4)));
typedef unsigned short ushort8 __attribute__((ext_vector_type(8)));
typedef __bf16 bf16x8 __attribute__((ext_vector_type(8)));
typedef float f32x4 __attribute__((ext_vector_type(4)));
typedef float f32x16 __attribute__((ext_vector_type(16)));

#define SEQ 4096
#define DIM 1024
#define NH 16
#define HD 64
// 0.125 * log2(e): folded into Q projection so softmax uses exp2 directly
#define QSCALE 0.18033688011112042f

#define LSTR 40                    // LDS row stride (elems): bank-safe
#define ABUF (128 * LSTR)
#define BBUF (64 * LSTR)

__device__ inline ushort_t fcvt(float f) {           // native f32->bf16 RTNE
    return __builtin_bit_cast(ushort_t, (__bf16)f);
}
__device__ inline bf16x8 frag_of(ushort8 t) {
    return __builtin_bit_cast(bf16x8, t);
}
__device__ inline bf16x8 lds_frag(const ushort_t* p) {
    return frag_of(*(const ushort8*)p);
}

// ---------------------------------------------------------------------------
// Prep: f32 -> bf16 converts
// ---------------------------------------------------------------------------
__global__ __launch_bounds__(256) void cvt2(
    const float* __restrict__ s0, ushort_t* __restrict__ d0,
    const float* __restrict__ s1, ushort_t* __restrict__ d1, int n8)
{
    const float* s = blockIdx.y ? s1 : s0;
    ushort_t*    d = blockIdx.y ? d1 : d0;
    int i = blockIdx.x * 256 + threadIdx.x;
    if (i >= n8) return;
    const f32x4* sp = (const f32x4*)s + (size_t)i * 2;
    f32x4 a = sp[0], b = sp[1];
    ushort8 o;
    for (int k = 0; k < 4; ++k) { o[k] = fcvt(a[k]); o[k + 4] = fcvt(b[k]); }
    *((ushort8*)d + i) = o;
}

__global__ __launch_bounds__(256) void cvt4(
    const float* __restrict__ s0, ushort_t* __restrict__ d0,
    const float* __restrict__ s1, ushort_t* __restrict__ d1,
    const float* __restrict__ s2, ushort_t* __restrict__ d2,
    const float* __restrict__ s3, ushort_t* __restrict__ d3, int n8)
{
    const float* ss[4] = {s0, s1, s2, s3};
    ushort_t*    dd[4] = {d0, d1, d2, d3};
    const float* s = ss[blockIdx.y];
    ushort_t*    d = dd[blockIdx.y];
    int i = blockIdx.x * 256 + threadIdx.x;
    if (i >= n8) return;
    const f32x4* sp = (const f32x4*)s + (size_t)i * 2;
    f32x4 a = sp[0], b = sp[1];
    ushort8 o;
    for (int k = 0; k < 4; ++k) { o[k] = fcvt(a[k]); o[k + 4] = fcvt(b[k]); }
    *((ushort8*)d + i) = o;
}

// ---------------------------------------------------------------------------
// Pipelined GEMM core (macro-free via always_inline device fn).
// Tile 128(M) x 64(N), BK=32, 256 thr = 4 waves 2x2; each wave 64x32 out
// as 4x2 tiles of 16x16x32.  Double-buffered LDS, register staging, one
// barrier per iter.  acc laid out acc[i][j].
// ---------------------------------------------------------------------------
__device__ __attribute__((always_inline)) inline void gemm_core(
    const ushort_t* __restrict__ A, const ushort_t* __restrict__ W,
    int m0, int n0, int tid, f32x4 (&acc)[4][2], ushort_t* sA, ushort_t* sB)
{
    const int lane = tid & 63;
    const int quad = lane >> 4;
    const int l15  = lane & 15;
    const int wm   = (tid >> 6) >> 1;
    const int wn   = (tid >> 6) & 1;

    // staging chunk indices
    const int ar0 = tid >> 2;                 // A rows 0..63  (chunk c=tid)
    const int ar1 = (tid + 256) >> 2;         // A rows 64..127
    const int ac  = (tid & 3) << 3;           // 0,8,16,24
    const int br  = tid >> 2;                 // B rows 0..63
    const ushort_t* Ag0 = A + (size_t)(m0 + ar0) * DIM + ac;
    const ushort_t* Ag1 = A + (size_t)(m0 + ar1) * DIM + ac;
    const ushort_t* Wg  = W + (size_t)(n0 + br) * DIM + ac;
    const int la0 = ar0 * LSTR + ac, la1 = ar1 * LSTR + ac, lb = br * LSTR + ac;

    // prologue: stage tile 0 into buffer 0
    *(ushort8*)(sA + la0) = *(const ushort8*)(Ag0);
    *(ushort8*)(sA + la1) = *(const ushort8*)(Ag1);
    *(ushort8*)(sB + lb)  = *(const ushort8*)(Wg);
    __syncthreads();

    for (int it = 0; it < DIM / 32; ++it) {
        const int cur = it & 1;
        const int ktn = (it + 1) * 32;
        ushort_t* aC = sA + cur * ABUF;
        ushort_t* bC = sB + cur * BBUF;

        // issue next tile's global loads (consumed ~full iter later)
        ushort8 ga0, ga1, gb0;
        if (ktn < DIM) {
            ga0 = *(const ushort8*)(Ag0 + ktn);
            ga1 = *(const ushort8*)(Ag1 + ktn);
            gb0 = *(const ushort8*)(Wg + ktn);
        }

        bf16x8 af[4], bf[2];
        for (int i = 0; i < 4; ++i)
            af[i] = lds_frag(aC + (wm * 64 + i * 16 + l15) * LSTR + quad * 8);
        for (int j = 0; j < 2; ++j)
            bf[j] = lds_frag(bC + (wn * 32 + j * 16 + l15) * LSTR + quad * 8);
        for (int i = 0; i < 4; ++i)
            for (int j = 0; j < 2; ++j)
                acc[i][j] = __builtin_amdgcn_mfma_f32_16x16x32_bf16(
                    af[i], bf[j], acc[i][j], 0, 0, 0);

        if (ktn < DIM) {
            ushort_t* aN = sA + (cur ^ 1) * ABUF;
            ushort_t* bN = sB + (cur ^ 1) * BBUF;
            *(ushort8*)(aN + la0) = ga0;
            *(ushort8*)(aN + la1) = ga1;
            *(ushort8*)(bN + lb)  = gb0;
        }
        __syncthreads();
    }
}

// Fused Q/K/V projections: z = 0 (Q, scaled), 1 (K), 2 (V, transposed out).
// grid = (DIM/64, SEQ/128, 3) = (16, 32, 3) = 1536 blocks.
__global__ __launch_bounds__(256) void proj3(
    const ushort_t* __restrict__ Qb, const ushort_t* __restrict__ KVb,
    const ushort_t* __restrict__ qwb, const ushort_t* __restrict__ kwb,
    const ushort_t* __restrict__ vwb,
    const float* __restrict__ q_b, const float* __restrict__ k_b,
    const float* __restrict__ v_b,
    ushort_t* __restrict__ Qp, ushort_t* __restrict__ Kp,
    ushort_t* __restrict__ VpT)
{
    __shared__ __align__(16) ushort_t sA[2 * ABUF];
    __shared__ __align__(16) ushort_t sB[2 * BBUF];

    const int z = blockIdx.z;
    const ushort_t* A = z ? KVb : Qb;
    const ushort_t* W = (z == 0) ? qwb : (z == 1 ? kwb : vwb);
    const float* bias = (z == 0) ? q_b : (z == 1 ? k_b : v_b);
    const int tid = threadIdx.x;
    const int m0 = blockIdx.y * 128;
    const int n0 = blockIdx.x * 64;

    f32x4 acc[4][2] = {};
    gemm_core(A, W, m0, n0, tid, acc, sA, sB);

    const int lane = tid & 63, quad = lane >> 4, l15 = lane & 15;
    const int wm = (tid >> 6) >> 1, wn = (tid >> 6) & 1;
    const float scale = (z == 0) ? QSCALE : 1.0f;

    for (int j = 0; j < 2; ++j) {
        int col = n0 + wn * 32 + j * 16 + l15;
        float bj = bias[col];
        for (int i = 0; i < 4; ++i) {
            int row = m0 + wm * 64 + i * 16 + quad * 4;
            if (z == 2) {          // V^T: [col][row], b64 store
                ushort4v o4;
                for (int r = 0; r < 4; ++r) o4[r] = fcvt(acc[i][j][r] + bj);
                *(ushort4v*)(VpT + (size_t)col * SEQ + row) = o4;
            } else {
                ushort_t* C = z ? Kp : Qp;
                for (int r = 0; r < 4; ++r)
                    C[(size_t)(row + r) * DIM + col] =
                        fcvt((acc[i][j][r] + bj) * scale);
            }
        }
    }
}

// O projection: f32 output.  grid = (16, 32).
__global__ __launch_bounds__(256) void gemm_out(
    const ushort_t* __restrict__ A, const ushort_t* __restrict__ W,
    const float* __restrict__ bias, float* __restrict__ C)
{
    __shared__ __align__(16) ushort_t sA[2 * ABUF];
    __shared__ __align__(16) ushort_t sB[2 * BBUF];

    const int tid = threadIdx.x;
    const int m0 = blockIdx.y * 128;
    const int n0 = blockIdx.x * 64;

    f32x4 acc[4][2] = {};
    gemm_core(A, W, m0, n0, tid, acc, sA, sB);

    const int lane = tid & 63, quad = lane >> 4, l15 = lane & 15;
    const int wm = (tid >> 6) >> 1, wn = (tid >> 6) & 1;
    for (int j = 0; j < 2; ++j) {
        int col = n0 + wn * 32 + j * 16 + l15;
        float bj = bias[col];
        for (int i = 0; i < 4; ++i) {
            int row = m0 + wm * 64 + i * 16 + quad * 4;
            for (int r = 0; r < 4; ++r)
                C[(size_t)(row + r) * DIM + col] = acc[i][j][r] + bj;
        }
    }
}

// ---------------------------------------------------------------------------
// Flash attention (unchanged from R11): 32x32x16 MFMA, zero-shift softmax,
// pipelined LDS staging, 4 waves x 32 q, kv tile 64, 2 barriers/iter.
// grid = (NH, SEQ/128) = (16, 32).
// ---------------------------------------------------------------------------
#define BUFE (2 * 64 * 72)
__global__ __launch_bounds__(256) void attn_kernel(
    const ushort_t* __restrict__ Q, const ushort_t* __restrict__ K,
    const ushort_t* __restrict__ VT, ushort_t* __restrict__ O)
{
    __shared__ __align__(16) ushort_t sB[2 * BUFE];   // 36864 B

    const int tid  = threadIdx.x;
    const int w    = tid >> 6;
    const int lane = tid & 63;
    const int l31  = lane & 31;
    const int hi   = lane >> 5;
    const int h    = blockIdx.x;
    const int q0   = blockIdx.y * 128 + w * 32;
    const int hHD  = h * HD;

    const int srow0 = tid >> 3;
    const int srow1 = (tid + 256) >> 3;
    const int sch   = (tid & 7) << 3;
    const ushort_t* Kg0 = K  + (size_t)srow0 * DIM + hHD + sch;
    const ushort_t* Kg1 = K  + (size_t)srow1 * DIM + hHD + sch;
    const ushort_t* Vg0 = VT + (size_t)(hHD + srow0) * SEQ + sch;
    const ushort_t* Vg1 = VT + (size_t)(hHD + srow1) * SEQ + sch;
    const int l0 = srow0 * 72 + sch, l1 = srow1 * 72 + sch;

    const ushort_t* qb = Q + (size_t)(q0 + l31) * DIM + hHD + hi * 8;
    bf16x8 qf[4];
    for (int ks = 0; ks < 4; ++ks)
        qf[ks] = frag_of(*(const ushort8*)(qb + ks * 16));

    *(ushort8*)(sB + l0)        = *(const ushort8*)(Kg0);
    *(ushort8*)(sB + l1)        = *(const ushort8*)(Kg1);
    *(ushort8*)(sB + 4608 + l0) = *(const ushort8*)(Vg0);
    *(ushort8*)(sB + 4608 + l1) = *(const ushort8*)(Vg1);
    __syncthreads();

    f32x16 oacc[2] = {};
    float l_i = 0.f;

    for (int it = 0; it < SEQ / 64; ++it) {
        const int cur = it & 1;
        const int kvn = (it + 1) * 64;
        ushort_t* bK = sB + cur * BUFE;
        ushort_t* bV = bK + 4608;

        ushort8 gk0, gk1, gv0, gv1;
        if (kvn < SEQ) {
            gk0 = *(const ushort8*)(Kg0 + (size_t)kvn * DIM);
            gk1 = *(const ushort8*)(Kg1 + (size_t)kvn * DIM);
            gv0 = *(const ushort8*)(Vg0 + kvn);
            gv1 = *(const ushort8*)(Vg1 + kvn);
        }

        bf16x8 kf[8], vf[8];
        for (int t = 0; t < 2; ++t)
            for (int ks = 0; ks < 4; ++ks)
                kf[t * 4 + ks] = lds_frag(bK + (t * 32 + l31) * 72 + ks * 16 + hi * 8);
        for (int ks = 0; ks < 4; ++ks)
            for (int dt = 0; dt < 2; ++dt)
                vf[ks * 2 + dt] = lds_frag(bV + (dt * 32 + l31) * 72 + ks * 16 + hi * 8);

        f32x16 sacc[2] = {};
        for (int t = 0; t < 2; ++t)
            for (int ks = 0; ks < 4; ++ks)
                sacc[t] = __builtin_amdgcn_mfma_f32_32x32x16_bf16(
                    kf[t * 4 + ks], qf[ks], sacc[t], 0, 0, 0);

        __syncthreads();

        float lp = 0.f;
        for (int t = 0; t < 2; ++t)
            for (int r = 0; r < 16; ++r) {
                float p = __builtin_amdgcn_exp2f(sacc[t][r]);
                sacc[t][r] = p;
                lp += p;
            }
        l_i += lp + __shfl_xor(lp, 32);

        ushort_t* pw = bK + w * 2304;
        for (int t = 0; t < 2; ++t)
            for (int g = 0; g < 4; ++g) {
                ushort4v pk;
                for (int r = 0; r < 4; ++r) pk[r] = fcvt(sacc[t][g * 4 + r]);
                *(ushort4v*)(pw + l31 * 72 + t * 32 + g * 8 + hi * 4) = pk;
            }

        for (int ks = 0; ks < 4; ++ks) {
            bf16x8 pf = lds_frag(pw + l31 * 72 + ks * 16 + hi * 8);
            for (int dt = 0; dt < 2; ++dt)
                oacc[dt] = __builtin_amdgcn_mfma_f32_32x32x16_bf16(
                    vf[ks * 2 + dt], pf, oacc[dt], 0, 0, 0);
        }

        if (kvn < SEQ) {
            ushort_t* nB = sB + (cur ^ 1) * BUFE;
            *(ushort8*)(nB + l0)        = gk0;
            *(ushort8*)(nB + l1)        = gk1;
            *(ushort8*)(nB + 4608 + l0) = gv0;
            *(ushort8*)(nB + 4608 + l1) = gv1;
        }
        __syncthreads();
    }

    float inv = 1.f / l_i;
    int qrow = q0 + l31;
    for (int dt = 0; dt < 2; ++dt)
        for (int g = 0; g < 4; ++g) {
            ushort4v o4;
            for (int r = 0; r < 4; ++r) o4[r] = fcvt(oacc[dt][g * 4 + r] * inv);
            *(ushort4v*)(O + (size_t)qrow * DIM + hHD + dt * 32 + g * 8 + hi * 4) = o4;
        }
}

// ---------------------------------------------------------------------------
extern "C" void kernel_launch(void* const* d_in, const int* in_sizes, int n_in,
                              void* d_out, int out_size, void* d_ws, size_t ws_size,
                              hipStream_t stream)
{
    const float* q   = (const float*)d_in[0];
    const float* kv  = (const float*)d_in[1];
    const float* q_w = (const float*)d_in[2];
    const float* q_b = (const float*)d_in[3];
    const float* k_w = (const float*)d_in[4];
    const float* k_b = (const float*)d_in[5];
    const float* v_w = (const float*)d_in[6];
    const float* v_b = (const float*)d_in[7];
    const float* o_w = (const float*)d_in[8];
    const float* o_b = (const float*)d_in[9];
    float* out = (float*)d_out;

    const size_t SD = (size_t)SEQ * DIM;
    const size_t WW = (size_t)DIM * DIM;
    ushort_t* Qp  = (ushort_t*)d_ws;          // bf16, pre-scaled by QSCALE
    ushort_t* Kp  = Qp + SD;
    ushort_t* VpT = Kp + SD;                  // V^T: [DIM][SEQ]
    ushort_t* AO  = VpT + SD;                 // attention out; aliases Qb
    ushort_t* Qb  = AO;                       // bf16(q) — dead before AO write
    ushort_t* KVb = AO + SD;
    ushort_t* qwb = KVb + SD;
    ushort_t* kwb = qwb + WW;
    ushort_t* vwb = kwb + WW;
    ushort_t* owb = vwb + WW;

    cvt2<<<dim3((unsigned)(SD / 8 / 256), 2), 256, 0, stream>>>(
        q, Qb, kv, KVb, (int)(SD / 8));
    cvt4<<<dim3((unsigned)(WW / 8 / 256), 4), 256, 0, stream>>>(
        q_w, qwb, k_w, kwb, v_w, vwb, o_w, owb, (int)(WW / 8));

    proj3<<<dim3(DIM / 64, SEQ / 128, 3), 256, 0, stream>>>(
        Qb, KVb, qwb, kwb, vwb, q_b, k_b, v_b, Qp, Kp, VpT);
    attn_kernel<<<dim3(NH, SEQ / 128), 256, 0, stream>>>(Qp, Kp, VpT, AO);
    gemm_out<<<dim3(DIM / 64, SEQ / 128), 256, 0, stream>>>(AO, owb, o_b, out);
}